// Round 10
// baseline (1609.693 us; speedup 1.0000x reference)
//
#include <hip/hip_runtime.h>
#include <stdint.h>

#define NN 2048
#define NCORE 8
#define TSIM 32
#define PLANE (256*2048)       // 512 KiB i8 plane

typedef int i4v __attribute__((ext_vector_type(4)));

__device__ __forceinline__ void load_lds16(const void* g, void* l) {
  __builtin_amdgcn_global_load_lds((const __attribute__((address_space(1))) void*)g,
                                   (__attribute__((address_space(3))) void*)l, 16, 0, 0);
}

// ---------------- zero init (flags) ----------------
__global__ void zero_f32_kernel(float* __restrict__ p, int n4) {
  int i = blockIdx.x * 256 + threadIdx.x;
  if (i < n4) ((float4*)p)[i] = make_float4(0.f, 0.f, 0.f, 0.f);
}

// ---------------- spike trains, i8 {0,1} ----------------
// byte(b,k) = b*2048 + (k>>6)*64 + ((((k>>4)&3) ^ ((b>>1)&3))<<4) + (k&15)
__global__ void spikes_kernel(const float* __restrict__ x, uint8_t* __restrict__ strain) {
  int gid = blockIdx.x * 256 + threadIdx.x;   // over 256*2048/16 = 32768
  int b = gid >> 7, kg = gid & 127;
  const float* xp = x + (size_t)b * NN + kg * 16;
  float nsf[16], sp[16]; int ns[16];
#pragma unroll
  for (int e = 0; e < 16; ++e) {
    float nv = rintf(xp[e] * 32.0f);
    nsf[e] = nv; ns[e] = (int)nv; sp[e] = 32.0f / fmaxf(nv, 1.0f);
  }
  uint32_t dst = (uint32_t)b * 2048 + ((uint32_t)(kg >> 2) << 6)
               + ((uint32_t)((kg & 3) ^ ((b >> 1) & 3)) << 4);
  int cyc0 = blockIdx.y * 4;
#pragma unroll
  for (int i = 0; i < 4; ++i) {
    int cyc = cyc0 + i;
    float ct = (float)cyc;
    uint32_t w[4] = {0u, 0u, 0u, 0u};
#pragma unroll
    for (int e = 0; e < 16; ++e) {
      bool res;
      if (ns[e] == TSIM)      res = true;
      else if (ns[e] == 0)    res = false;
      else {
        float q = floorf(ct / sp[e]);
        float m = fmodf(ct, sp[e]);
        res = (q < nsf[e]) && (floorf(m) == 0.0f);
      }
      if (res) w[e >> 2] |= 1u << ((e & 3) * 8);
    }
    uint4 pk; pk.x = w[0]; pk.y = w[1]; pk.z = w[2]; pk.w = w[3];
    *(uint4*)(strain + (size_t)cyc * PLANE + dst) = pk;
  }
}

// ---------------- W split: exact i8 3-plane fixed point (R6 layout, z=core) ----------------
__global__ __launch_bounds__(256) void wsplit_kernel(const float* __restrict__ W,
                                                     uint8_t* __restrict__ Whm) {
  __shared__ uint32_t lds[3 * 2048];
  int kk = blockIdx.x, nt = blockIdx.y, c = blockIdx.z;
  int tid = threadIdx.x, lane = tid & 63, wid = tid >> 6;
  const float* src = W + ((size_t)c * NN + (size_t)kk * 128) * NN + nt * 64 + lane;
#pragma unroll
  for (int kp = 0; kp < 8; ++kp) {
    uint32_t pk0 = 0, pk1 = 0, pk2 = 0;
#pragma unroll
    for (int q = 0; q < 4; ++q) {
      int kl = kp * 16 + wid * 4 + q;
      float w = src[(size_t)kl * NN];
      int wi = (int)rintf(w * 0x1p25f);
      int l8 = (int)(int8_t)(uint8_t)(wi & 0xFF);
      int r1 = (wi - l8) >> 8;
      int m8 = (int)(int8_t)(uint8_t)(r1 & 0xFF);
      int h8 = (r1 - m8) >> 8;
      pk0 |= ((uint32_t)(uint8_t)h8) << (q * 8);
      pk1 |= ((uint32_t)(uint8_t)m8) << (q * 8);
      pk2 |= ((uint32_t)(uint8_t)l8) << (q * 8);
    }
    int kq = kp * 4 + wid;
    lds[0 * 2048 + kq * 64 + lane] = pk0;
    lds[1 * 2048 + kq * 64 + lane] = pk1;
    lds[2 * 2048 + kq * 64 + lane] = pk2;
  }
  __syncthreads();
  size_t chunkbase = (((size_t)c * 32 + nt) * 16 + kk) * 24576;
#pragma unroll
  for (int g = 0; g < 6; ++g) {
    int idx = g * 256 + tid;
    int ks2 = (idx >= 768) ? 1 : 0;
    int rem = idx - ks2 * 768;
    int p = rem >> 8;
    int n = (rem >> 2) & 63;
    int s = rem & 3;
    int k16 = s ^ ((n >> 1) & 3);
    int kqb = ks2 * 16 + k16 * 4;
    uint4 v;
    v.x = lds[p * 2048 + (kqb + 0) * 64 + n];
    v.y = lds[p * 2048 + (kqb + 1) * 64 + n];
    v.z = lds[p * 2048 + (kqb + 2) * 64 + n];
    v.w = lds[p * 2048 + (kqb + 3) * 64 + n];
    *(uint4*)(Whm + chunkbase + (size_t)idx * 16) = v;
  }
}

// ---------------- persistent pipelined simulation ----------------
// grid 256 blocks (1/CU): block = (c = bid&7, nt = bid>>3); 16 pairs of local steps.
__global__ __launch_bounds__(512) void sim_kernel(
    const uint8_t* __restrict__ Whm, const float* __restrict__ thresholds,
    const uint8_t* __restrict__ strain, uint8_t* __restrict__ bufs,
    int* fdone, int* fcons, float* __restrict__ out) {
  __shared__ uint8_t smem[157696];   // A0 2x16K | A1 2x16K | B 2x12K | memb [256][66] f32

  const int tid = threadIdx.x;
  const int bid = blockIdx.x;
  const int c = bid & 7, nt = bid >> 3;
  const int l = tid & 63, wid = tid >> 6;
  const int wm = wid >> 1, wn = wid & 1;
  const int lr = l & 15, lh = l >> 4;
  float* membL = (float*)(smem + 90112);
  for (int i = tid; i < 16896; i += 512) membL[i] = 0.f;
  __syncthreads();

  const float thr = thresholds[c];
  const uint32_t swz = (uint32_t)(lh ^ ((lr >> 1) & 3)) << 4;
  const uint32_t aoff_base = (uint32_t)(wm * 64 + lr) * 64 + swz;
  const uint32_t boff_base = (uint32_t)(wn * 32 + lr) * 64 + swz;
  const uint32_t aoff_t = (uint32_t)(tid >> 2) * 2048 + (uint32_t)(tid & 3) * 16;
  const uint8_t* wbase = Whm + (((size_t)c * 32 + nt) * 16) * 24576;
  uint32_t cnt[8] = {0, 0, 0, 0, 0, 0, 0, 0};

#define WAITV6() asm volatile("s_waitcnt vmcnt(6)" ::: "memory")
#define WAITV5() asm volatile("s_waitcnt vmcnt(5)" ::: "memory")
#define WAITV0() asm volatile("s_waitcnt vmcnt(0)" ::: "memory")
#define WAITL() asm volatile("s_waitcnt lgkmcnt(0)" ::: "memory")
#define BAR() do { __builtin_amdgcn_s_barrier(); __builtin_amdgcn_sched_barrier(0); } while (0)

  for (int jj = 0; jj < 16; ++jj) {
    // ---- wait for producer core's pair jj ----
    if (c > 0) {
      if (tid == 0) {
        int* f = &fdone[(c - 1) * 16 + jj];
        while (__hip_atomic_load(f, __ATOMIC_RELAXED, __HIP_MEMORY_SCOPE_AGENT) < 32)
          __builtin_amdgcn_s_sleep(8);
        __threadfence();   // acquire: invalidate stale caches
      }
      __syncthreads();
    }
    const int s0 = 2 * jj, s1 = 2 * jj + 1;
    const uint8_t* pl0 = (c == 0) ? strain + (size_t)s0 * PLANE
                                  : bufs + ((size_t)(c - 1) * 8 + (s0 & 7)) * PLANE;
    const uint8_t* pl1 = (c == 0) ? strain + (size_t)s1 * PLANE
                                  : bufs + ((size_t)(c - 1) * 8 + (s1 & 7)) * PLANE;
    const uint8_t* a0 = pl0 + aoff_t;
    const uint8_t* a1 = pl1 + aoff_t;

    i4v acc[2][3][4][2];
    const i4v izero = {0, 0, 0, 0};
#pragma unroll
    for (int st = 0; st < 2; ++st)
#pragma unroll
      for (int p = 0; p < 3; ++p)
#pragma unroll
        for (int mi = 0; mi < 4; ++mi) {
          acc[st][p][mi][0] = izero; acc[st][p][mi][1] = izero;
        }

    auto issue = [&](int k, int slot) {
      uint8_t* A0d = smem + slot * 16384;
      uint8_t* A1d = smem + 32768 + slot * 16384;
      uint8_t* Bd  = smem + 65536 + slot * 12288;
      load_lds16(a0 + k * 64,          A0d + tid * 16);
      load_lds16(a0 + 262144 + k * 64, A0d + 8192 + tid * 16);
      load_lds16(a1 + k * 64,          A1d + tid * 16);
      load_lds16(a1 + 262144 + k * 64, A1d + 8192 + tid * 16);
      const uint8_t* bsrc = wbase + (size_t)(k >> 1) * 24576 + (size_t)(k & 1) * 12288;
      load_lds16(bsrc + tid * 16, Bd + tid * 16);
      if (tid < 256) load_lds16(bsrc + (512 + tid) * 16, Bd + (512 + tid) * 16);
    };

    auto comp = [&](int slot) {
      const uint8_t* A0b = smem + slot * 16384;
      const uint8_t* A1b = smem + 32768 + slot * 16384;
      const uint8_t* Bb  = smem + 65536 + slot * 12288;
      i4v bf[3][2];
#pragma unroll
      for (int p = 0; p < 3; ++p) {
        bf[p][0] = *(const i4v*)(Bb + p * 4096 + boff_base);
        bf[p][1] = *(const i4v*)(Bb + p * 4096 + boff_base + 1024);
      }
      __builtin_amdgcn_s_setprio(1);
#pragma unroll
      for (int mi = 0; mi < 4; ++mi) {
        i4v a_ = *(const i4v*)(A0b + aoff_base + mi * 1024);
#pragma unroll
        for (int p = 0; p < 3; ++p) {
          acc[0][p][mi][0] = __builtin_amdgcn_mfma_i32_16x16x64_i8(a_, bf[p][0], acc[0][p][mi][0], 0, 0, 0);
          acc[0][p][mi][1] = __builtin_amdgcn_mfma_i32_16x16x64_i8(a_, bf[p][1], acc[0][p][mi][1], 0, 0, 0);
        }
      }
#pragma unroll
      for (int mi = 0; mi < 4; ++mi) {
        i4v a_ = *(const i4v*)(A1b + aoff_base + mi * 1024);
#pragma unroll
        for (int p = 0; p < 3; ++p) {
          acc[1][p][mi][0] = __builtin_amdgcn_mfma_i32_16x16x64_i8(a_, bf[p][0], acc[1][p][mi][0], 0, 0, 0);
          acc[1][p][mi][1] = __builtin_amdgcn_mfma_i32_16x16x64_i8(a_, bf[p][1], acc[1][p][mi][1], 0, 0, 0);
        }
      }
      __builtin_amdgcn_s_setprio(0);
    };

    issue(0, 0);
    for (int k = 0; k < 32; ++k) {
      if (k < 31) {
        issue(k + 1, (k + 1) & 1);
        if (tid < 256) { WAITV6(); } else { WAITV5(); }
      } else {
        WAITV0();
      }
      BAR();
      comp(k & 1);
      WAITL();
      BAR();
    }

    // ---- signal reads done; backpressure before overwriting planes ----
    if (c > 0 && tid == 0)
      __hip_atomic_fetch_add(&fcons[(c - 1) * 16 + jj], 1, __ATOMIC_RELAXED,
                             __HIP_MEMORY_SCOPE_AGENT);
    if (c < 7 && jj >= 4) {
      if (tid == 0) {
        int* f = &fcons[c * 16 + (jj - 4)];
        while (__hip_atomic_load(f, __ATOMIC_RELAXED, __HIP_MEMORY_SCOPE_AGENT) < 32)
          __builtin_amdgcn_s_sleep(8);
      }
      __syncthreads();
    }

    // ---- epilogue: exact recombine, membrane (LDS), fire, buf/counts ----
    uint8_t* b0p = bufs + ((size_t)c * 8 + (s0 & 7)) * PLANE;
    uint8_t* b1p = bufs + ((size_t)c * 8 + (s1 & 7)) * PLANE;
#pragma unroll
    for (int mi = 0; mi < 4; ++mi)
#pragma unroll
      for (int nj = 0; nj < 2; ++nj)
#pragma unroll
        for (int rg = 0; rg < 4; ++rg) {
          int row = wm * 64 + mi * 16 + lh * 4 + rg;
          int col = wn * 32 + nj * 16 + lr;
          float* mp = &membL[row * 66 + col];
          float m = *mp;
          int d0 = (acc[0][0][mi][nj][rg] << 16) + (acc[0][1][mi][nj][rg] << 8)
                 + acc[0][2][mi][nj][rg];
          m += (float)d0 * 0x1p-25f;
          bool f0 = thr < m; if (f0) m -= thr;
          int d1 = (acc[1][0][mi][nj][rg] << 16) + (acc[1][1][mi][nj][rg] << 8)
                 + acc[1][2][mi][nj][rg];
          m += (float)d1 * 0x1p-25f;
          bool f1 = thr < m; if (f1) m -= thr;
          *mp = m;
          if (c < 7) {
            // FIX (R9 bug): global neuron index o = nt*64 + col -> group byte nt<<6
            uint32_t ba = (uint32_t)row * 2048 + ((uint32_t)nt << 6)
                        + ((uint32_t)(((col >> 4) & 3) ^ ((row >> 1) & 3)) << 4) + (col & 15);
            b0p[ba] = f0 ? 1 : 0;
            b1p[ba] = f1 ? 1 : 0;
          } else {
            int e = (mi * 2 + nj) * 4 + rg;
            cnt[e >> 2] += ((f0 ? 1u : 0u) + (f1 ? 1u : 0u)) << ((e & 3) * 8);
          }
        }
    if (c < 7) {
      __syncthreads();               // drains all waves' stores (vmcnt 0)
      if (tid == 0) {
        __threadfence();             // release: write back L2
        __hip_atomic_fetch_add(&fdone[c * 16 + jj], 1, __ATOMIC_RELAXED,
                               __HIP_MEMORY_SCOPE_AGENT);
      }
    }
  }

  // ---- final output (core 7 fully covers out) ----
  if (c == 7) {
#pragma unroll
    for (int mi = 0; mi < 4; ++mi)
#pragma unroll
      for (int nj = 0; nj < 2; ++nj)
#pragma unroll
        for (int rg = 0; rg < 4; ++rg) {
          int row = wm * 64 + mi * 16 + lh * 4 + rg;
          int col = wn * 32 + nj * 16 + lr;
          int e = (mi * 2 + nj) * 4 + rg;
          float cv = (float)((cnt[e >> 2] >> ((e & 3) * 8)) & 0xFFu);
          out[(size_t)row * NN + nt * 64 + col] = cv * 0x1p-5f;
        }
  }
#undef WAITV6
#undef WAITV5
#undef WAITV0
#undef WAITL
#undef BAR
}

extern "C" void kernel_launch(void* const* d_in, const int* in_sizes, int n_in,
                              void* d_out, int out_size, void* d_ws, size_t ws_size,
                              hipStream_t stream) {
  const float* x   = (const float*)d_in[0];
  const float* W   = (const float*)d_in[1];
  const float* thr = (const float*)d_in[2];
  float* out = (float*)d_out;
  uint8_t* ws = (uint8_t*)d_ws;

  // layout: flags 64K | strain 16.78M | bufs 29.36M (7 cores x 8 planes) | Whm 100.66M
  int*     fdone  = (int*)ws;                    // [8][16]
  int*     fcons  = (int*)(ws + 2048);           // [8][16]
  uint8_t* strain = ws + 65536;
  uint8_t* bufs   = ws + 65536 + 16777216;       // 16,842,752
  uint8_t* Whm    = ws + 65536 + 16777216 + 29360128;   // 46,202,880

  zero_f32_kernel<<<dim3(1), 256, 0, stream>>>((float*)ws, 256);   // flags (4 KB)
  spikes_kernel<<<dim3(128, 8), 256, 0, stream>>>(x, strain);
  wsplit_kernel<<<dim3(16, 32, 8), 256, 0, stream>>>(W, Whm);
  sim_kernel<<<dim3(256), 512, 0, stream>>>(Whm, thr, strain, bufs, fdone, fcons, out);
}

// Round 11
// 1205.426 us; speedup vs baseline: 1.3354x; 1.3354x over previous
//
#include <hip/hip_runtime.h>
#include <stdint.h>

#define NN 2048
#define NCORE 8
#define TSIM 32
#define PLANE (256*2048)       // 512 KiB i8 plane

typedef int i4v __attribute__((ext_vector_type(4)));

__device__ __forceinline__ void load_lds16(const void* g, void* l) {
  __builtin_amdgcn_global_load_lds((const __attribute__((address_space(1))) void*)g,
                                   (__attribute__((address_space(3))) void*)l, 16, 0, 0);
}

// ---------------- zero init ----------------
__global__ void zero_f32_kernel(float* __restrict__ p, int n4) {
  int i = blockIdx.x * 256 + threadIdx.x;
  if (i < n4) ((float4*)p)[i] = make_float4(0.f, 0.f, 0.f, 0.f);
}

// ---------------- spike trains, i8 {0,1}, 64B-group 2-bit swizzle ----------------
// byte(b,k) = b*2048 + (k>>6)*64 + ((((k>>4)&3) ^ ((b>>1)&3))<<4) + (k&15)
__global__ void spikes_kernel(const float* __restrict__ x, uint8_t* __restrict__ strain) {
  int gid = blockIdx.x * 256 + threadIdx.x;   // over 256*2048/16 = 32768
  int b = gid >> 7, kg = gid & 127;
  const float* xp = x + (size_t)b * NN + kg * 16;
  float nsf[16], sp[16]; int ns[16];
#pragma unroll
  for (int e = 0; e < 16; ++e) {
    float nv = rintf(xp[e] * 32.0f);
    nsf[e] = nv; ns[e] = (int)nv; sp[e] = 32.0f / fmaxf(nv, 1.0f);
  }
  uint32_t dst = (uint32_t)b * 2048 + ((uint32_t)(kg >> 2) << 6)
               + ((uint32_t)((kg & 3) ^ ((b >> 1) & 3)) << 4);
  int cyc0 = blockIdx.y * 4;
#pragma unroll
  for (int i = 0; i < 4; ++i) {
    int cyc = cyc0 + i;
    float ct = (float)cyc;
    uint32_t w[4] = {0u, 0u, 0u, 0u};
#pragma unroll
    for (int e = 0; e < 16; ++e) {
      bool res;
      if (ns[e] == TSIM)      res = true;
      else if (ns[e] == 0)    res = false;
      else {
        float q = floorf(ct / sp[e]);
        float m = fmodf(ct, sp[e]);
        res = (q < nsf[e]) && (floorf(m) == 0.0f);
      }
      if (res) w[e >> 2] |= 1u << ((e & 3) * 8);
    }
    uint4 pk; pk.x = w[0]; pk.y = w[1]; pk.z = w[2]; pk.w = w[3];
    *(uint4*)(strain + (size_t)cyc * PLANE + dst) = pk;
  }
}

// ---------------- W split: exact i8 3-plane fixed point ----------------
__global__ __launch_bounds__(256) void wsplit_kernel(const float* __restrict__ W,
                                                     uint8_t* __restrict__ Whm) {
  __shared__ uint32_t lds[3 * 2048];
  int kk = blockIdx.x, nt = blockIdx.y, c = blockIdx.z;
  int tid = threadIdx.x, lane = tid & 63, wid = tid >> 6;
  const float* src = W + ((size_t)c * NN + (size_t)kk * 128) * NN + nt * 64 + lane;
#pragma unroll
  for (int kp = 0; kp < 8; ++kp) {
    uint32_t pk0 = 0, pk1 = 0, pk2 = 0;
#pragma unroll
    for (int q = 0; q < 4; ++q) {
      int kl = kp * 16 + wid * 4 + q;
      float w = src[(size_t)kl * NN];
      int wi = (int)rintf(w * 0x1p25f);
      int l8 = (int)(int8_t)(uint8_t)(wi & 0xFF);
      int r1 = (wi - l8) >> 8;
      int m8 = (int)(int8_t)(uint8_t)(r1 & 0xFF);
      int h8 = (r1 - m8) >> 8;
      pk0 |= ((uint32_t)(uint8_t)h8) << (q * 8);
      pk1 |= ((uint32_t)(uint8_t)m8) << (q * 8);
      pk2 |= ((uint32_t)(uint8_t)l8) << (q * 8);
    }
    int kq = kp * 4 + wid;
    lds[0 * 2048 + kq * 64 + lane] = pk0;
    lds[1 * 2048 + kq * 64 + lane] = pk1;
    lds[2 * 2048 + kq * 64 + lane] = pk2;
  }
  __syncthreads();
  size_t chunkbase = (((size_t)c * 32 + nt) * 16 + kk) * 24576;
#pragma unroll
  for (int g = 0; g < 6; ++g) {
    int idx = g * 256 + tid;
    int ks2 = (idx >= 768) ? 1 : 0;
    int rem = idx - ks2 * 768;
    int p = rem >> 8;
    int n = (rem >> 2) & 63;
    int s = rem & 3;
    int k16 = s ^ ((n >> 1) & 3);
    int kqb = ks2 * 16 + k16 * 4;
    uint4 v;
    v.x = lds[p * 2048 + (kqb + 0) * 64 + n];
    v.y = lds[p * 2048 + (kqb + 1) * 64 + n];
    v.z = lds[p * 2048 + (kqb + 2) * 64 + n];
    v.w = lds[p * 2048 + (kqb + 3) * 64 + n];
    *(uint4*)(Whm + chunkbase + (size_t)idx * 16) = v;
  }
}

// ---------------- dual-step skewed dispatch: core c does steps 2j-c, 2j-c+1 ----------------
// grid (active cores, 32 n-tiles), 512 threads. W[c] streamed ONCE per 2 steps.
__global__ __launch_bounds__(512) void step2_kernel(
    const uint8_t* __restrict__ Whm, const float* __restrict__ thresholds,
    const uint8_t* __restrict__ strain, uint8_t* bufs,
    float* __restrict__ memb, float* __restrict__ out, int j, int c_lo) {
  __shared__ uint8_t smem[90112];   // A0 2x16K | A1 2x16K | B 2x12K; epilogue overlay 2x34816B

  const int tid = threadIdx.x;
  const int c = c_lo + blockIdx.x;
  const int nt = blockIdx.y;
  const int s0 = 2 * j - c, s1 = s0 + 1;
  const int l = tid & 63, wid = tid >> 6;
  const int wm = wid >> 1, wn = wid & 1;
  const int lr = l & 15, lh = l >> 4;

  const uint8_t* pl0 = (c == 0) ? strain + (size_t)s0 * PLANE
                                : bufs + ((size_t)(c - 1) * 4 + ((s0 - 1) & 3)) * PLANE;
  const uint8_t* pl1 = (c == 0) ? strain + (size_t)s1 * PLANE
                                : bufs + ((size_t)(c - 1) * 4 + ((s1 - 1) & 3)) * PLANE;
  const uint32_t aoff_t = (uint32_t)(tid >> 2) * 2048 + (uint32_t)(tid & 3) * 16;
  const uint8_t* a0 = pl0 + aoff_t;
  const uint8_t* a1 = pl1 + aoff_t;
  const uint8_t* wbase = Whm + (((size_t)c * 32 + nt) * 16) * 24576;

  const uint32_t swz = (uint32_t)(lh ^ ((lr >> 1) & 3)) << 4;
  const uint32_t aoff_base = (uint32_t)(wm * 64 + lr) * 64 + swz;
  const uint32_t boff_base = (uint32_t)(wn * 32 + lr) * 64 + swz;

  i4v acc[2][3][4][2];
  const i4v izero = {0, 0, 0, 0};
#pragma unroll
  for (int st = 0; st < 2; ++st)
#pragma unroll
    for (int p = 0; p < 3; ++p)
#pragma unroll
      for (int mi = 0; mi < 4; ++mi) {
        acc[st][p][mi][0] = izero; acc[st][p][mi][1] = izero;
      }

  auto issue = [&](int k, int slot) {
    uint8_t* A0d = smem + slot * 16384;
    uint8_t* A1d = smem + 32768 + slot * 16384;
    uint8_t* Bd  = smem + 65536 + slot * 12288;
    load_lds16(a0 + k * 64,          A0d + tid * 16);
    load_lds16(a0 + 262144 + k * 64, A0d + 8192 + tid * 16);
    load_lds16(a1 + k * 64,          A1d + tid * 16);
    load_lds16(a1 + 262144 + k * 64, A1d + 8192 + tid * 16);
    const uint8_t* bsrc = wbase + (size_t)(k >> 1) * 24576 + (size_t)(k & 1) * 12288;
    load_lds16(bsrc + tid * 16, Bd + tid * 16);
    if (tid < 256) load_lds16(bsrc + (512 + tid) * 16, Bd + (512 + tid) * 16);
  };

  auto comp = [&](int slot) {
    const uint8_t* A0b = smem + slot * 16384;
    const uint8_t* A1b = smem + 32768 + slot * 16384;
    const uint8_t* Bb  = smem + 65536 + slot * 12288;
    i4v bf[3][2];
#pragma unroll
    for (int p = 0; p < 3; ++p) {
      bf[p][0] = *(const i4v*)(Bb + p * 4096 + boff_base);
      bf[p][1] = *(const i4v*)(Bb + p * 4096 + boff_base + 1024);
    }
    __builtin_amdgcn_s_setprio(1);
#pragma unroll
    for (int mi = 0; mi < 4; ++mi) {
      i4v a_ = *(const i4v*)(A0b + aoff_base + mi * 1024);
#pragma unroll
      for (int p = 0; p < 3; ++p) {
        acc[0][p][mi][0] = __builtin_amdgcn_mfma_i32_16x16x64_i8(a_, bf[p][0], acc[0][p][mi][0], 0, 0, 0);
        acc[0][p][mi][1] = __builtin_amdgcn_mfma_i32_16x16x64_i8(a_, bf[p][1], acc[0][p][mi][1], 0, 0, 0);
      }
    }
#pragma unroll
    for (int mi = 0; mi < 4; ++mi) {
      i4v a_ = *(const i4v*)(A1b + aoff_base + mi * 1024);
#pragma unroll
      for (int p = 0; p < 3; ++p) {
        acc[1][p][mi][0] = __builtin_amdgcn_mfma_i32_16x16x64_i8(a_, bf[p][0], acc[1][p][mi][0], 0, 0, 0);
        acc[1][p][mi][1] = __builtin_amdgcn_mfma_i32_16x16x64_i8(a_, bf[p][1], acc[1][p][mi][1], 0, 0, 0);
      }
    }
    __builtin_amdgcn_s_setprio(0);
  };

#define WAITV6() asm volatile("s_waitcnt vmcnt(6)" ::: "memory")
#define WAITV5() asm volatile("s_waitcnt vmcnt(5)" ::: "memory")
#define WAITV0() asm volatile("s_waitcnt vmcnt(0)" ::: "memory")
#define WAITL() asm volatile("s_waitcnt lgkmcnt(0)" ::: "memory")
#define BAR() do { __builtin_amdgcn_s_barrier(); __builtin_amdgcn_sched_barrier(0); } while (0)

  issue(0, 0);
  for (int k = 0; k < 32; ++k) {
    if (k < 31) {
      issue(k + 1, (k + 1) & 1);
      if (tid < 256) { WAITV6(); } else { WAITV5(); }
    } else {
      WAITV0();
    }
    BAR();
    comp(k & 1);
    WAITL();
    BAR();
  }
#undef WAITV6
#undef WAITV5
#undef WAITV0
#undef WAITL
#undef BAR

  // ---- epilogue: two-phase transpose, dual-fire membrane update ----
  __syncthreads();
  const float thr = thresholds[c];
  float* Cl0 = (float*)smem;                 // [128][68] f32
  float* Cl1 = (float*)(smem + 34816);
  float* membp = memb + (size_t)c * PLANE;
  uint8_t* b0p = bufs + ((size_t)c * 4 + (s0 & 3)) * PLANE;
  uint8_t* b1p = bufs + ((size_t)c * 4 + (s1 & 3)) * PLANE;
  const bool last = (j == 22);
#pragma unroll
  for (int h = 0; h < 2; ++h) {
    if (h) __syncthreads();
    if ((wm >> 1) == h) {
#pragma unroll
      for (int mi = 0; mi < 4; ++mi)
#pragma unroll
        for (int nj = 0; nj < 2; ++nj)
#pragma unroll
          for (int rg = 0; rg < 4; ++rg) {
            int row = wm * 64 + mi * 16 + lh * 4 + rg - h * 128;
            int col = wn * 32 + nj * 16 + lr;
            int d0 = (acc[0][0][mi][nj][rg] << 16) + (acc[0][1][mi][nj][rg] << 8)
                   + acc[0][2][mi][nj][rg];
            int d1 = (acc[1][0][mi][nj][rg] << 16) + (acc[1][1][mi][nj][rg] << 8)
                   + acc[1][2][mi][nj][rg];
            Cl0[row * 68 + col] = (float)d0 * 0x1p-25f;
            Cl1[row * 68 + col] = (float)d1 * 0x1p-25f;
          }
    }
    __syncthreads();
#pragma unroll
    for (int p = 0; p < 4; ++p) {
      int rr = p * 32 + (tid >> 4);
      int c4 = (tid & 15) * 4;
      int b = h * 128 + rr;
      int o = nt * 64 + c4;
      float4 d0 = *(const float4*)&Cl0[rr * 68 + c4];
      float4 d1 = *(const float4*)&Cl1[rr * 68 + c4];
      size_t idx = (size_t)b * NN + o;
      float4 mv = *(float4*)(membp + idx);
      mv.x += d0.x; mv.y += d0.y; mv.z += d0.z; mv.w += d0.w;
      bool f0x = thr < mv.x, f0y = thr < mv.y, f0z = thr < mv.z, f0w = thr < mv.w;
      if (f0x) mv.x -= thr;  if (f0y) mv.y -= thr;
      if (f0z) mv.z -= thr;  if (f0w) mv.w -= thr;
      mv.x += d1.x; mv.y += d1.y; mv.z += d1.z; mv.w += d1.w;
      bool f1x = thr < mv.x, f1y = thr < mv.y, f1z = thr < mv.z, f1w = thr < mv.w;
      if (f1x) mv.x -= thr;  if (f1y) mv.y -= thr;
      if (f1z) mv.z -= thr;  if (f1w) mv.w -= thr;
      *(float4*)(membp + idx) = mv;
      if (c < 7) {
        uint32_t ba = (uint32_t)b * 2048 + ((uint32_t)(o >> 6) << 6)
                    + ((uint32_t)(((o >> 4) & 3) ^ ((b >> 1) & 3)) << 4) + (o & 15);
        uchar4 p0, p1;
        p0.x = f0x ? 1 : 0; p0.y = f0y ? 1 : 0; p0.z = f0z ? 1 : 0; p0.w = f0w ? 1 : 0;
        p1.x = f1x ? 1 : 0; p1.y = f1y ? 1 : 0; p1.z = f1z ? 1 : 0; p1.w = f1w ? 1 : 0;
        *(uchar4*)(b0p + ba) = p0;
        *(uchar4*)(b1p + ba) = p1;
      } else {
        float4 cv = *(float4*)(out + idx);
        cv.x += (f0x ? 1.f : 0.f) + (f1x ? 1.f : 0.f);
        cv.y += (f0y ? 1.f : 0.f) + (f1y ? 1.f : 0.f);
        cv.z += (f0z ? 1.f : 0.f) + (f1z ? 1.f : 0.f);
        cv.w += (f0w ? 1.f : 0.f) + (f1w ? 1.f : 0.f);
        if (last) { cv.x *= 0x1p-5f; cv.y *= 0x1p-5f; cv.z *= 0x1p-5f; cv.w *= 0x1p-5f; }
        *(float4*)(out + idx) = cv;
      }
    }
  }
}

extern "C" void kernel_launch(void* const* d_in, const int* in_sizes, int n_in,
                              void* d_out, int out_size, void* d_ws, size_t ws_size,
                              hipStream_t stream) {
  const float* x   = (const float*)d_in[0];
  const float* W   = (const float*)d_in[1];
  const float* thr = (const float*)d_in[2];
  float* out = (float*)d_out;
  uint8_t* ws = (uint8_t*)d_ws;

  // layout: memb f32 16.78M | strain 16.78M | bufs 7x4 planes 14.68M | Whm 100.66M
  float*   memb   = (float*)ws;
  uint8_t* strain = ws + 16777216;
  uint8_t* bufs   = ws + 33554432;
  uint8_t* Whm    = ws + 48234496;

  zero_f32_kernel<<<dim3(4096), 256, 0, stream>>>(memb, 1048576);
  zero_f32_kernel<<<dim3(512),  256, 0, stream>>>(out, 131072);
  spikes_kernel<<<dim3(128, 8), 256, 0, stream>>>(x, strain);
  wsplit_kernel<<<dim3(16, 32, 8), 256, 0, stream>>>(W, Whm);

  for (int j = 0; j < 23; ++j) {      // core c does steps 2j-c, 2j-c+1 (j in [c, c+15])
    int c_lo = (j > 15) ? (j - 15) : 0;
    int c_hi = (j < 7) ? j : 7;
    step2_kernel<<<dim3(c_hi - c_lo + 1, 32), 512, 0, stream>>>(
        Whm, thr, strain, bufs, memb, out, j, c_lo);
  }
}

// Round 12
// 1064.691 us; speedup vs baseline: 1.5119x; 1.1322x over previous
//
#include <hip/hip_runtime.h>
#include <stdint.h>

#define NN 2048
#define NCORE 8
#define TSIM 32
#define PLANE (256*2048)       // 512 KiB i8 plane

typedef int i4v __attribute__((ext_vector_type(4)));

__device__ __forceinline__ void load_lds16(const void* g, void* l) {
  __builtin_amdgcn_global_load_lds((const __attribute__((address_space(1))) void*)g,
                                   (__attribute__((address_space(3))) void*)l, 16, 0, 0);
}

// ---------------- zero init ----------------
__global__ void zero_f32_kernel(float* __restrict__ p, int n4) {
  int i = blockIdx.x * 256 + threadIdx.x;
  if (i < n4) ((float4*)p)[i] = make_float4(0.f, 0.f, 0.f, 0.f);
}

// ---------------- spike trains, i8 {0,1}, 64B-group 2-bit swizzle ----------------
// byte(b,k) = b*2048 + (k>>6)*64 + ((((k>>4)&3) ^ ((b>>1)&3))<<4) + (k&15)
__global__ void spikes_kernel(const float* __restrict__ x, uint8_t* __restrict__ strain) {
  int gid = blockIdx.x * 256 + threadIdx.x;   // over 256*2048/16 = 32768
  int b = gid >> 7, kg = gid & 127;
  const float* xp = x + (size_t)b * NN + kg * 16;
  float nsf[16], sp[16]; int ns[16];
#pragma unroll
  for (int e = 0; e < 16; ++e) {
    float nv = rintf(xp[e] * 32.0f);
    nsf[e] = nv; ns[e] = (int)nv; sp[e] = 32.0f / fmaxf(nv, 1.0f);
  }
  uint32_t dst = (uint32_t)b * 2048 + ((uint32_t)(kg >> 2) << 6)
               + ((uint32_t)((kg & 3) ^ ((b >> 1) & 3)) << 4);
  int cyc0 = blockIdx.y * 4;
#pragma unroll
  for (int i = 0; i < 4; ++i) {
    int cyc = cyc0 + i;
    float ct = (float)cyc;
    uint32_t w[4] = {0u, 0u, 0u, 0u};
#pragma unroll
    for (int e = 0; e < 16; ++e) {
      bool res;
      if (ns[e] == TSIM)      res = true;
      else if (ns[e] == 0)    res = false;
      else {
        float q = floorf(ct / sp[e]);
        float m = fmodf(ct, sp[e]);
        res = (q < nsf[e]) && (floorf(m) == 0.0f);
      }
      if (res) w[e >> 2] |= 1u << ((e & 3) * 8);
    }
    uint4 pk; pk.x = w[0]; pk.y = w[1]; pk.z = w[2]; pk.w = w[3];
    *(uint4*)(strain + (size_t)cyc * PLANE + dst) = pk;
  }
}

// ---------------- W split: exact i8 3-plane fixed point ----------------
__global__ __launch_bounds__(256) void wsplit_kernel(const float* __restrict__ W,
                                                     uint8_t* __restrict__ Whm) {
  __shared__ uint32_t lds[3 * 2048];
  int kk = blockIdx.x, nt = blockIdx.y, c = blockIdx.z;
  int tid = threadIdx.x, lane = tid & 63, wid = tid >> 6;
  const float* src = W + ((size_t)c * NN + (size_t)kk * 128) * NN + nt * 64 + lane;
#pragma unroll
  for (int kp = 0; kp < 8; ++kp) {
    uint32_t pk0 = 0, pk1 = 0, pk2 = 0;
#pragma unroll
    for (int q = 0; q < 4; ++q) {
      int kl = kp * 16 + wid * 4 + q;
      float w = src[(size_t)kl * NN];
      int wi = (int)rintf(w * 0x1p25f);
      int l8 = (int)(int8_t)(uint8_t)(wi & 0xFF);
      int r1 = (wi - l8) >> 8;
      int m8 = (int)(int8_t)(uint8_t)(r1 & 0xFF);
      int h8 = (r1 - m8) >> 8;
      pk0 |= ((uint32_t)(uint8_t)h8) << (q * 8);
      pk1 |= ((uint32_t)(uint8_t)m8) << (q * 8);
      pk2 |= ((uint32_t)(uint8_t)l8) << (q * 8);
    }
    int kq = kp * 4 + wid;
    lds[0 * 2048 + kq * 64 + lane] = pk0;
    lds[1 * 2048 + kq * 64 + lane] = pk1;
    lds[2 * 2048 + kq * 64 + lane] = pk2;
  }
  __syncthreads();
  size_t chunkbase = (((size_t)c * 32 + nt) * 16 + kk) * 24576;
#pragma unroll
  for (int g = 0; g < 6; ++g) {
    int idx = g * 256 + tid;
    int ks2 = (idx >= 768) ? 1 : 0;
    int rem = idx - ks2 * 768;
    int p = rem >> 8;
    int n = (rem >> 2) & 63;
    int s = rem & 3;
    int k16 = s ^ ((n >> 1) & 3);
    int kqb = ks2 * 16 + k16 * 4;
    uint4 v;
    v.x = lds[p * 2048 + (kqb + 0) * 64 + n];
    v.y = lds[p * 2048 + (kqb + 1) * 64 + n];
    v.z = lds[p * 2048 + (kqb + 2) * 64 + n];
    v.w = lds[p * 2048 + (kqb + 3) * 64 + n];
    *(uint4*)(Whm + chunkbase + (size_t)idx * 16) = v;
  }
}

// ---------------- dual-step skewed dispatch, 128-row blocks, 2 blocks/CU ----------------
// grid (active cores, 64): y = rh*32? no: nt = y&31, rh = y>>5. core c does steps 2j-c, 2j-c+1.
__global__ __launch_bounds__(512, 4) void step2_kernel(
    const uint8_t* __restrict__ Whm, const float* __restrict__ thresholds,
    const uint8_t* __restrict__ strain, uint8_t* bufs,
    float* __restrict__ memb, float* __restrict__ out, int j, int c_lo) {
  __shared__ uint8_t smem[57344];   // A: 2steps x 2buf x 8K | B: 2buf x 12K; epilogue [128][68] f32

  const int tid = threadIdx.x;
  const int c = c_lo + blockIdx.x;
  const int yy = blockIdx.y;
  const int nt = yy & 31, rh = yy >> 5;
  const int s0 = 2 * j - c, s1 = s0 + 1;
  const int l = tid & 63, wid = tid >> 6;
  const int wm = wid >> 1, wn = wid & 1;     // 32-row x 32-col wave tiles
  const int lr = l & 15, lh = l >> 4;

  const uint8_t* pl0 = (c == 0) ? strain + (size_t)s0 * PLANE
                                : bufs + ((size_t)(c - 1) * 4 + ((s0 - 1) & 3)) * PLANE;
  const uint8_t* pl1 = (c == 0) ? strain + (size_t)s1 * PLANE
                                : bufs + ((size_t)(c - 1) * 4 + ((s1 - 1) & 3)) * PLANE;
  const uint32_t arow = (uint32_t)(rh * 128 + (tid >> 2));
  const uint32_t aoff_t = arow * 2048 + (uint32_t)(tid & 3) * 16;
  const uint8_t* a0 = pl0 + aoff_t;
  const uint8_t* a1 = pl1 + aoff_t;
  const uint8_t* wbase = Whm + (((size_t)c * 32 + nt) * 16) * 24576;

  const uint32_t swz = (uint32_t)(lh ^ ((lr >> 1) & 3)) << 4;
  const uint32_t aoff = (uint32_t)(wm * 32 + lr) * 64 + swz;   // + mi*1024
  const uint32_t boff = (uint32_t)(wn * 32 + lr) * 64 + swz;   // + p*4096 + nj*1024

  i4v acc[2][3][2][2];
  const i4v izero = {0, 0, 0, 0};
#pragma unroll
  for (int st = 0; st < 2; ++st)
#pragma unroll
    for (int p = 0; p < 3; ++p)
#pragma unroll
      for (int mi = 0; mi < 2; ++mi) {
        acc[st][p][mi][0] = izero; acc[st][p][mi][1] = izero;
      }

  auto issue = [&](int k, int slot) {
    uint8_t* A0d = smem + slot * 8192;
    uint8_t* A1d = smem + 16384 + slot * 8192;
    uint8_t* Bd  = smem + 32768 + slot * 12288;
    load_lds16(a0 + k * 64, A0d + tid * 16);
    load_lds16(a1 + k * 64, A1d + tid * 16);
    const uint8_t* bs = wbase + (size_t)(k >> 1) * 24576 + (size_t)(k & 1) * 12288;
    load_lds16(bs + tid * 16, Bd + tid * 16);
    if (tid < 256) load_lds16(bs + 8192 + tid * 16, Bd + 8192 + tid * 16);
  };

  auto comp = [&](int slot) {
    const uint8_t* A0b = smem + slot * 8192;
    const uint8_t* A1b = smem + 16384 + slot * 8192;
    const uint8_t* Bb  = smem + 32768 + slot * 12288;
    i4v a00 = *(const i4v*)(A0b + aoff);
    i4v a01 = *(const i4v*)(A0b + aoff + 1024);
    i4v a10 = *(const i4v*)(A1b + aoff);
    i4v a11 = *(const i4v*)(A1b + aoff + 1024);
    __builtin_amdgcn_s_setprio(1);
#pragma unroll
    for (int p = 0; p < 3; ++p) {
      i4v bf0 = *(const i4v*)(Bb + p * 4096 + boff);
      i4v bf1 = *(const i4v*)(Bb + p * 4096 + boff + 1024);
      acc[0][p][0][0] = __builtin_amdgcn_mfma_i32_16x16x64_i8(a00, bf0, acc[0][p][0][0], 0, 0, 0);
      acc[0][p][0][1] = __builtin_amdgcn_mfma_i32_16x16x64_i8(a00, bf1, acc[0][p][0][1], 0, 0, 0);
      acc[0][p][1][0] = __builtin_amdgcn_mfma_i32_16x16x64_i8(a01, bf0, acc[0][p][1][0], 0, 0, 0);
      acc[0][p][1][1] = __builtin_amdgcn_mfma_i32_16x16x64_i8(a01, bf1, acc[0][p][1][1], 0, 0, 0);
      acc[1][p][0][0] = __builtin_amdgcn_mfma_i32_16x16x64_i8(a10, bf0, acc[1][p][0][0], 0, 0, 0);
      acc[1][p][0][1] = __builtin_amdgcn_mfma_i32_16x16x64_i8(a10, bf1, acc[1][p][0][1], 0, 0, 0);
      acc[1][p][1][0] = __builtin_amdgcn_mfma_i32_16x16x64_i8(a11, bf0, acc[1][p][1][0], 0, 0, 0);
      acc[1][p][1][1] = __builtin_amdgcn_mfma_i32_16x16x64_i8(a11, bf1, acc[1][p][1][1], 0, 0, 0);
    }
    __builtin_amdgcn_s_setprio(0);
  };

#define WAITV(n) asm volatile("s_waitcnt vmcnt(" #n ")" ::: "memory")
#define WAITL() asm volatile("s_waitcnt lgkmcnt(0)" ::: "memory")
#define BAR() do { __builtin_amdgcn_s_barrier(); __builtin_amdgcn_sched_barrier(0); } while (0)

  issue(0, 0);
  for (int k = 0; k < 32; ++k) {
    if (k < 31) {
      issue(k + 1, (k + 1) & 1);
      if (tid < 256) { WAITV(4); } else { WAITV(3); }
    } else {
      WAITV(0);
    }
    BAR();
    comp(k & 1);
    WAITL();
    BAR();
  }
#undef WAITV
#undef WAITL
#undef BAR

  // ---- epilogue: per-step transpose through [128][68] LDS, dual-fire update ----
  __syncthreads();
  const float thr = thresholds[c];
  float* Cl = (float*)smem;
  float* membp = memb + (size_t)c * PLANE;
  uint8_t* b0p = bufs + ((size_t)c * 4 + (s0 & 3)) * PLANE;
  uint8_t* b1p = bufs + ((size_t)c * 4 + (s1 & 3)) * PLANE;
  const bool last = (j == 22);

  float4 d0[4];
#pragma unroll
  for (int st = 0; st < 2; ++st) {
    if (st) __syncthreads();
#pragma unroll
    for (int mi = 0; mi < 2; ++mi)
#pragma unroll
      for (int nj = 0; nj < 2; ++nj)
#pragma unroll
        for (int rg = 0; rg < 4; ++rg) {
          int row = wm * 32 + mi * 16 + lh * 4 + rg;
          int col = wn * 32 + nj * 16 + lr;
          int di = (acc[st][0][mi][nj][rg] << 16) + (acc[st][1][mi][nj][rg] << 8)
                 + acc[st][2][mi][nj][rg];
          Cl[row * 68 + col] = (float)di * 0x1p-25f;
        }
    __syncthreads();
    if (st == 0) {
#pragma unroll
      for (int p = 0; p < 4; ++p) {
        int rr = p * 32 + (tid >> 4);
        int c4 = (tid & 15) * 4;
        d0[p] = *(const float4*)&Cl[rr * 68 + c4];
      }
    } else {
#pragma unroll
      for (int p = 0; p < 4; ++p) {
        int rr = p * 32 + (tid >> 4);
        int c4 = (tid & 15) * 4;
        float4 d1 = *(const float4*)&Cl[rr * 68 + c4];
        int b = rh * 128 + rr;
        int o = nt * 64 + c4;
        size_t idx = (size_t)b * NN + o;
        float4 mv = *(float4*)(membp + idx);
        mv.x += d0[p].x; mv.y += d0[p].y; mv.z += d0[p].z; mv.w += d0[p].w;
        bool f0x = thr < mv.x, f0y = thr < mv.y, f0z = thr < mv.z, f0w = thr < mv.w;
        if (f0x) mv.x -= thr;  if (f0y) mv.y -= thr;
        if (f0z) mv.z -= thr;  if (f0w) mv.w -= thr;
        mv.x += d1.x; mv.y += d1.y; mv.z += d1.z; mv.w += d1.w;
        bool f1x = thr < mv.x, f1y = thr < mv.y, f1z = thr < mv.z, f1w = thr < mv.w;
        if (f1x) mv.x -= thr;  if (f1y) mv.y -= thr;
        if (f1z) mv.z -= thr;  if (f1w) mv.w -= thr;
        *(float4*)(membp + idx) = mv;
        if (c < 7) {
          uint32_t ba = (uint32_t)b * 2048 + ((uint32_t)(o >> 6) << 6)
                      + ((uint32_t)(((o >> 4) & 3) ^ ((b >> 1) & 3)) << 4) + (o & 15);
          uchar4 p0, p1;
          p0.x = f0x ? 1 : 0; p0.y = f0y ? 1 : 0; p0.z = f0z ? 1 : 0; p0.w = f0w ? 1 : 0;
          p1.x = f1x ? 1 : 0; p1.y = f1y ? 1 : 0; p1.z = f1z ? 1 : 0; p1.w = f1w ? 1 : 0;
          *(uchar4*)(b0p + ba) = p0;
          *(uchar4*)(b1p + ba) = p1;
        } else {
          float4 cv = *(float4*)(out + idx);
          cv.x += (f0x ? 1.f : 0.f) + (f1x ? 1.f : 0.f);
          cv.y += (f0y ? 1.f : 0.f) + (f1y ? 1.f : 0.f);
          cv.z += (f0z ? 1.f : 0.f) + (f1z ? 1.f : 0.f);
          cv.w += (f0w ? 1.f : 0.f) + (f1w ? 1.f : 0.f);
          if (last) { cv.x *= 0x1p-5f; cv.y *= 0x1p-5f; cv.z *= 0x1p-5f; cv.w *= 0x1p-5f; }
          *(float4*)(out + idx) = cv;
        }
      }
    }
  }
}

extern "C" void kernel_launch(void* const* d_in, const int* in_sizes, int n_in,
                              void* d_out, int out_size, void* d_ws, size_t ws_size,
                              hipStream_t stream) {
  const float* x   = (const float*)d_in[0];
  const float* W   = (const float*)d_in[1];
  const float* thr = (const float*)d_in[2];
  float* out = (float*)d_out;
  uint8_t* ws = (uint8_t*)d_ws;

  // layout: memb f32 16.78M | strain 16.78M | bufs 7x4 planes 14.68M | Whm 100.66M
  float*   memb   = (float*)ws;
  uint8_t* strain = ws + 16777216;
  uint8_t* bufs   = ws + 33554432;
  uint8_t* Whm    = ws + 48234496;

  zero_f32_kernel<<<dim3(4096), 256, 0, stream>>>(memb, 1048576);
  zero_f32_kernel<<<dim3(512),  256, 0, stream>>>(out, 131072);
  spikes_kernel<<<dim3(128, 8), 256, 0, stream>>>(x, strain);
  wsplit_kernel<<<dim3(16, 32, 8), 256, 0, stream>>>(W, Whm);

  for (int j = 0; j < 23; ++j) {      // core c does steps 2j-c, 2j-c+1 (j in [c, c+15])
    int c_lo = (j > 15) ? (j - 15) : 0;
    int c_hi = (j < 7) ? j : 7;
    step2_kernel<<<dim3(c_hi - c_lo + 1, 64), 512, 0, stream>>>(
        Whm, thr, strain, bufs, memb, out, j, c_lo);
  }
}

// Round 13
// 811.482 us; speedup vs baseline: 1.9836x; 1.3120x over previous
//
#include <hip/hip_runtime.h>
#include <stdint.h>

#define NN 2048
#define NCORE 8
#define TSIM 32
#define PLANE (256*2048)       // 512 KiB i8 plane

typedef int i4v __attribute__((ext_vector_type(4)));

__device__ __forceinline__ void load_lds16(const void* g, void* l) {
  __builtin_amdgcn_global_load_lds((const __attribute__((address_space(1))) void*)g,
                                   (__attribute__((address_space(3))) void*)l, 16, 0, 0);
}

// ---------------- zero init ----------------
__global__ void zero_f32_kernel(float* __restrict__ p, int n4) {
  int i = blockIdx.x * 256 + threadIdx.x;
  if (i < n4) ((float4*)p)[i] = make_float4(0.f, 0.f, 0.f, 0.f);
}

// ---------------- spike trains, i8 {0,1}, 64B-group 2-bit swizzle ----------------
// byte(b,k) = b*2048 + (k>>6)*64 + ((((k>>4)&3) ^ ((b>>1)&3))<<4) + (k&15)
__global__ void spikes_kernel(const float* __restrict__ x, uint8_t* __restrict__ strain) {
  int gid = blockIdx.x * 256 + threadIdx.x;   // over 256*2048/16 = 32768
  int b = gid >> 7, kg = gid & 127;
  const float* xp = x + (size_t)b * NN + kg * 16;
  float nsf[16], sp[16]; int ns[16];
#pragma unroll
  for (int e = 0; e < 16; ++e) {
    float nv = rintf(xp[e] * 32.0f);
    nsf[e] = nv; ns[e] = (int)nv; sp[e] = 32.0f / fmaxf(nv, 1.0f);
  }
  uint32_t dst = (uint32_t)b * 2048 + ((uint32_t)(kg >> 2) << 6)
               + ((uint32_t)((kg & 3) ^ ((b >> 1) & 3)) << 4);
  int cyc0 = blockIdx.y * 4;
#pragma unroll
  for (int i = 0; i < 4; ++i) {
    int cyc = cyc0 + i;
    float ct = (float)cyc;
    uint32_t w[4] = {0u, 0u, 0u, 0u};
#pragma unroll
    for (int e = 0; e < 16; ++e) {
      bool res;
      if (ns[e] == TSIM)      res = true;
      else if (ns[e] == 0)    res = false;
      else {
        float q = floorf(ct / sp[e]);
        float m = fmodf(ct, sp[e]);
        res = (q < nsf[e]) && (floorf(m) == 0.0f);
      }
      if (res) w[e >> 2] |= 1u << ((e & 3) * 8);
    }
    uint4 pk; pk.x = w[0]; pk.y = w[1]; pk.z = w[2]; pk.w = w[3];
    *(uint4*)(strain + (size_t)cyc * PLANE + dst) = pk;
  }
}

// ---------------- W split: exact i8 3-plane fixed point ----------------
__global__ __launch_bounds__(256) void wsplit_kernel(const float* __restrict__ W,
                                                     uint8_t* __restrict__ Whm) {
  __shared__ uint32_t lds[3 * 2048];
  int kk = blockIdx.x, nt = blockIdx.y, c = blockIdx.z;
  int tid = threadIdx.x, lane = tid & 63, wid = tid >> 6;
  const float* src = W + ((size_t)c * NN + (size_t)kk * 128) * NN + nt * 64 + lane;
#pragma unroll
  for (int kp = 0; kp < 8; ++kp) {
    uint32_t pk0 = 0, pk1 = 0, pk2 = 0;
#pragma unroll
    for (int q = 0; q < 4; ++q) {
      int kl = kp * 16 + wid * 4 + q;
      float w = src[(size_t)kl * NN];
      int wi = (int)rintf(w * 0x1p25f);
      int l8 = (int)(int8_t)(uint8_t)(wi & 0xFF);
      int r1 = (wi - l8) >> 8;
      int m8 = (int)(int8_t)(uint8_t)(r1 & 0xFF);
      int h8 = (r1 - m8) >> 8;
      pk0 |= ((uint32_t)(uint8_t)h8) << (q * 8);
      pk1 |= ((uint32_t)(uint8_t)m8) << (q * 8);
      pk2 |= ((uint32_t)(uint8_t)l8) << (q * 8);
    }
    int kq = kp * 4 + wid;
    lds[0 * 2048 + kq * 64 + lane] = pk0;
    lds[1 * 2048 + kq * 64 + lane] = pk1;
    lds[2 * 2048 + kq * 64 + lane] = pk2;
  }
  __syncthreads();
  size_t chunkbase = (((size_t)c * 32 + nt) * 16 + kk) * 24576;
#pragma unroll
  for (int g = 0; g < 6; ++g) {
    int idx = g * 256 + tid;
    int ks2 = (idx >= 768) ? 1 : 0;
    int rem = idx - ks2 * 768;
    int p = rem >> 8;
    int n = (rem >> 2) & 63;
    int s = rem & 3;
    int k16 = s ^ ((n >> 1) & 3);
    int kqb = ks2 * 16 + k16 * 4;
    uint4 v;
    v.x = lds[p * 2048 + (kqb + 0) * 64 + n];
    v.y = lds[p * 2048 + (kqb + 1) * 64 + n];
    v.z = lds[p * 2048 + (kqb + 2) * 64 + n];
    v.w = lds[p * 2048 + (kqb + 3) * 64 + n];
    *(uint4*)(Whm + chunkbase + (size_t)idx * 16) = v;
  }
}

// ---------------- quad-step skewed dispatch: core c does local steps 4(j-c)..+3 ----------------
// grid (active cores, 128): nt = y&31, rq = y>>5 (64-row group). W streamed once per 4 steps.
__global__ __launch_bounds__(512, 4) void step4_kernel(
    const uint8_t* __restrict__ Whm, const float* __restrict__ thresholds,
    const uint8_t* __restrict__ strain, uint8_t* bufs,
    float* __restrict__ memb, float* __restrict__ out, int j, int c_lo) {
  __shared__ uint8_t smem[57344];   // A: 4st x 2buf x 4K | B: 2buf x 12K; epilogue [64][68] f32

  const int tid = threadIdx.x;
  const int c = c_lo + blockIdx.x;
  const int yy = blockIdx.y;
  const int nt = yy & 31, rq = yy >> 5;
  const int sl = 4 * (j - c);                // local step base (0..28)
  const int l = tid & 63, wid = tid >> 6;
  const int wm = wid >> 2, wn = wid & 3;     // 32-row x 16-col wave tiles
  const int lr = l & 15, lh = l >> 4;

  // input planes for the 4 steps
  const uint8_t* pls[4];
#pragma unroll
  for (int st = 0; st < 4; ++st)
    pls[st] = (c == 0) ? strain + (size_t)(sl + st) * PLANE
                       : bufs + ((size_t)(c - 1) * 8 + ((sl + st) & 7)) * PLANE;

  // per-thread A DMA sources: 2 loads, gi = j_*512+tid; si = gi>>8, idx = gi&255
  const uint8_t* ab[2];
  uint32_t adst[2];
#pragma unroll
  for (int j_ = 0; j_ < 2; ++j_) {
    int gi = j_ * 512 + tid;
    int si = gi >> 8, idx = gi & 255;
    int row = idx >> 2, kq = idx & 3;
    ab[j_] = pls[si] + (size_t)(rq * 64 + row) * 2048 + kq * 16;
    adst[j_] = si * 8192 + idx * 16;        // + slot*4096
  }
  const uint8_t* wbase = Whm + (((size_t)c * 32 + nt) * 16) * 24576;
  uint8_t* Bs = smem + 32768;

  const uint32_t swz = (uint32_t)(lh ^ ((lr >> 1) & 3)) << 4;
  const uint32_t aoff = (uint32_t)(wm * 32 + lr) * 64 + swz;   // + st*8192 + slot*4096 + mi*1024
  const uint32_t boff = (uint32_t)(wn * 16 + lr) * 64 + swz;   // + p*4096

  i4v acc[4][3][2];
  const i4v izero = {0, 0, 0, 0};
#pragma unroll
  for (int st = 0; st < 4; ++st)
#pragma unroll
    for (int p = 0; p < 3; ++p) { acc[st][p][0] = izero; acc[st][p][1] = izero; }

  auto issue = [&](int k, int slot) {
#pragma unroll
    for (int j_ = 0; j_ < 2; ++j_)
      load_lds16(ab[j_] + k * 64, smem + adst[j_] + slot * 4096);
    const uint8_t* bs = wbase + (size_t)(k >> 1) * 24576 + (size_t)(k & 1) * 12288;
    uint8_t* Bd = Bs + slot * 12288;
    load_lds16(bs + tid * 16, Bd + tid * 16);
    if (tid < 256) load_lds16(bs + 8192 + tid * 16, Bd + 8192 + tid * 16);
  };

  auto comp = [&](int slot) {
    const uint8_t* Bb = Bs + slot * 12288;
    i4v bf0 = *(const i4v*)(Bb + 0 * 4096 + boff);
    i4v bf1 = *(const i4v*)(Bb + 1 * 4096 + boff);
    i4v bf2 = *(const i4v*)(Bb + 2 * 4096 + boff);
    __builtin_amdgcn_s_setprio(1);
#pragma unroll
    for (int st = 0; st < 4; ++st) {
      const uint8_t* Ab = smem + st * 8192 + slot * 4096;
#pragma unroll
      for (int mi = 0; mi < 2; ++mi) {
        i4v a_ = *(const i4v*)(Ab + aoff + mi * 1024);
        acc[st][0][mi] = __builtin_amdgcn_mfma_i32_16x16x64_i8(a_, bf0, acc[st][0][mi], 0, 0, 0);
        acc[st][1][mi] = __builtin_amdgcn_mfma_i32_16x16x64_i8(a_, bf1, acc[st][1][mi], 0, 0, 0);
        acc[st][2][mi] = __builtin_amdgcn_mfma_i32_16x16x64_i8(a_, bf2, acc[st][2][mi], 0, 0, 0);
      }
    }
    __builtin_amdgcn_s_setprio(0);
  };

#define WAITV(n) asm volatile("s_waitcnt vmcnt(" #n ")" ::: "memory")
#define WAITL() asm volatile("s_waitcnt lgkmcnt(0)" ::: "memory")
#define BAR() do { __builtin_amdgcn_s_barrier(); __builtin_amdgcn_sched_barrier(0); } while (0)

  issue(0, 0);
  for (int k = 0; k < 32; ++k) {
    if (k < 31) {
      issue(k + 1, (k + 1) & 1);
      if (tid < 256) { WAITV(4); } else { WAITV(3); }
    } else {
      WAITV(0);
    }
    BAR();
    comp(k & 1);
    WAITL();
    BAR();
  }
#undef WAITV
#undef WAITL
#undef BAR

  // ---- epilogue: 4 sequential transposes, then single memb RMW with 4 ordered fires ----
  const float thr = thresholds[c];
  float* Cl = (float*)smem;                  // [64][68] f32 = 17408 B
  float4 d[4][2];
#pragma unroll
  for (int st = 0; st < 4; ++st) {
    __syncthreads();
#pragma unroll
    for (int mi = 0; mi < 2; ++mi)
#pragma unroll
      for (int rg = 0; rg < 4; ++rg) {
        int row = wm * 32 + mi * 16 + lh * 4 + rg;
        int col = wn * 16 + lr;
        int di = (acc[st][0][mi][rg] << 16) + (acc[st][1][mi][rg] << 8) + acc[st][2][mi][rg];
        Cl[row * 68 + col] = (float)di * 0x1p-25f;   // single RNE rounding of exact sum
      }
    __syncthreads();
#pragma unroll
    for (int p = 0; p < 2; ++p) {
      int rr = p * 32 + (tid >> 4);
      int c4 = (tid & 15) * 4;
      d[st][p] = *(const float4*)&Cl[rr * 68 + c4];
    }
  }

  float* membp = memb + (size_t)c * PLANE;
  uint8_t* bps[4];
#pragma unroll
  for (int st = 0; st < 4; ++st)
    bps[st] = bufs + ((size_t)c * 8 + ((sl + st) & 7)) * PLANE;
  const bool last = (j == 14);
#pragma unroll
  for (int p = 0; p < 2; ++p) {
    int rr = p * 32 + (tid >> 4);
    int c4 = (tid & 15) * 4;
    int b = rq * 64 + rr;
    int o = nt * 64 + c4;
    size_t idx = (size_t)b * NN + o;
    float4 mv = *(float4*)(membp + idx);
    float4 cv;
    if (c == 7) cv = *(float4*)(out + idx);
    uint32_t ba = (uint32_t)b * 2048 + ((uint32_t)(o >> 6) << 6)
                + ((uint32_t)(((o >> 4) & 3) ^ ((b >> 1) & 3)) << 4) + (o & 15);
#pragma unroll
    for (int st = 0; st < 4; ++st) {
      mv.x += d[st][p].x; mv.y += d[st][p].y; mv.z += d[st][p].z; mv.w += d[st][p].w;
      bool fx = thr < mv.x, fy = thr < mv.y, fz = thr < mv.z, fw = thr < mv.w;
      if (fx) mv.x -= thr;  if (fy) mv.y -= thr;
      if (fz) mv.z -= thr;  if (fw) mv.w -= thr;
      if (c < 7) {
        uchar4 pk;
        pk.x = fx ? 1 : 0; pk.y = fy ? 1 : 0; pk.z = fz ? 1 : 0; pk.w = fw ? 1 : 0;
        *(uchar4*)(bps[st] + ba) = pk;
      } else {
        cv.x += fx ? 1.f : 0.f; cv.y += fy ? 1.f : 0.f;
        cv.z += fz ? 1.f : 0.f; cv.w += fw ? 1.f : 0.f;
      }
    }
    *(float4*)(membp + idx) = mv;
    if (c == 7) {
      if (last) { cv.x *= 0x1p-5f; cv.y *= 0x1p-5f; cv.z *= 0x1p-5f; cv.w *= 0x1p-5f; }
      *(float4*)(out + idx) = cv;
    }
  }
}

extern "C" void kernel_launch(void* const* d_in, const int* in_sizes, int n_in,
                              void* d_out, int out_size, void* d_ws, size_t ws_size,
                              hipStream_t stream) {
  const float* x   = (const float*)d_in[0];
  const float* W   = (const float*)d_in[1];
  const float* thr = (const float*)d_in[2];
  float* out = (float*)d_out;
  uint8_t* ws = (uint8_t*)d_ws;

  // layout: memb f32 16.78M | strain 16.78M | bufs 7x8 planes 29.36M | Whm 100.66M
  float*   memb   = (float*)ws;
  uint8_t* strain = ws + 16777216;
  uint8_t* bufs   = ws + 33554432;
  uint8_t* Whm    = ws + 62914560;

  zero_f32_kernel<<<dim3(4096), 256, 0, stream>>>(memb, 1048576);
  zero_f32_kernel<<<dim3(512),  256, 0, stream>>>(out, 131072);
  spikes_kernel<<<dim3(128, 8), 256, 0, stream>>>(x, strain);
  wsplit_kernel<<<dim3(16, 32, 8), 256, 0, stream>>>(W, Whm);

  for (int j = 0; j < 15; ++j) {      // core c does local steps 4(j-c)..+3, active for c<=j<=c+7
    int c_lo = (j > 7) ? (j - 7) : 0;
    int c_hi = (j < 7) ? j : 7;
    step4_kernel<<<dim3(c_hi - c_lo + 1, 128), 512, 0, stream>>>(
        Whm, thr, strain, bufs, memb, out, j, c_lo);
  }
}